// Round 5
// baseline (204.854 us; speedup 1.0000x reference)
//
#include <hip/hip_runtime.h>
#include <math.h>

// Problem constants (from reference)
#define GRID_HW   13
#define NBOX      5
#define NCLASS    80
#define REC       85                       // 5 + NCLASS floats per cell
#define CPB_CELLS (GRID_HW*GRID_HW*NBOX)   // 845 cells per batch element
#define T_BOXES   50
#define THREADS   512
#define CPT       32                       // cells per tile
#define LPC       16                       // lanes per cell (80 classes / 5 each)
#define TILE_FLOATS (CPT*REC)              // 2720 floats per array per tile
#define TILE_F4     (TILE_FLOATS/4)        // 680 float4 per array per tile
#define MAX_GRID  3380                     // keeps partials footprint == proven 216 KB

__device__ __constant__ float c_anchors[10] = {
    0.57273f, 0.677385f, 1.87446f, 2.06253f, 3.33843f,
    5.47434f, 7.88282f, 3.52778f, 9.77052f, 9.16828f};

// partial row per block (64 B): [0]=sum_xy [1]=sum_wh [2]=sum_conf [3]=sum_ce
// [4]=nb_coord [5]=nb_conf [6]=nb_class [7]=0 pad (for double4 in reducer)
template <int USE_ATOMIC>
__global__ __launch_bounds__(THREADS, 8)
void yolo_loss_main(const float* __restrict__ y_true,
                    const float* __restrict__ y_pred,
                    const float* __restrict__ tboxes,
                    double* __restrict__ partials,
                    int n_cells, int ntiles)
{
    __shared__ float4 lbuf4[2 * TILE_F4];     // 21760 B staged tile (yt | yp)
    __shared__ double red[8][8];              // 8 waves

    float* const lt = (float*)lbuf4;          // y_true tile
    float* const lp = lt + TILE_FLOATS;       // y_pred tile

    const int tid = threadIdx.x;
    const int g   = tid & (LPC - 1);          // lane within cell group (0..15)
    const int cl  = tid >> 4;                 // cell within tile (0..31)

    double p_xy = 0.0, p_wh = 0.0, p_conf = 0.0, p_ce = 0.0;
    double p_nc = 0.0, p_nf = 0.0, p_ncl = 0.0;

    for (int tile = blockIdx.x; tile < ntiles; tile += gridDim.x) {
        __syncthreads();                      // prior tile fully consumed

        // ---- stage tile: perfectly coalesced float4 global -> LDS ----
        const int cellbase = tile * CPT;
        const int remc = min(CPT, n_cells - cellbase);
        if (remc == CPT) {
            const float4* __restrict__ gt4 = (const float4*)(y_true + (size_t)cellbase * REC);
            const float4* __restrict__ gp4 = (const float4*)(y_pred + (size_t)cellbase * REC);
            #pragma unroll
            for (int r = 0; r < 3; ++r) {
                const int idx = r * THREADS + tid;
                if (idx < 2 * TILE_F4)
                    lbuf4[idx] = (idx < TILE_F4) ? gt4[idx] : gp4[idx - TILE_F4];
            }
        } else {
            const int nf = remc * REC;
            const size_t base = (size_t)cellbase * REC;
            for (int i = tid; i < nf; i += THREADS) {
                lt[i] = y_true[base + i];
                lp[i] = y_pred[base + i];
            }
        }
        __syncthreads();

        const int cell = cellbase + cl;
        if (cell < n_cells) {
            // decode (b, h, w, box)
            int b    = cell / CPB_CELLS;
            int rem  = cell - b * CPB_CELLS;
            int h    = rem / (GRID_HW * NBOX);
            int rem2 = rem - h * (GRID_HW * NBOX);
            int w    = rem2 / NBOX;
            int box  = rem2 - w * NBOX;

            const float* __restrict__ yt = lt + cl * REC;
            const float* __restrict__ yp = lp + cl * REC;

            // head (LDS broadcast reads within the 16-lane group -> free)
            const float tx = yt[0], ty = yt[1], tw = yt[2], th = yt[3], yt4 = yt[4];
            const float r0 = yp[0], r1 = yp[1], r2 = yp[2], r3 = yp[3], r4 = yp[4];

            const float px = 1.f / (1.f + expf(-r0)) + (float)w;
            const float py = 1.f / (1.f + expf(-r1)) + (float)h;
            const float pw = expf(r2) * c_anchors[2 * box];
            const float ph = expf(r3) * c_anchors[2 * box + 1];
            const float pconf = 1.f / (1.f + expf(-r4));

            const float pw2 = pw * 0.5f, ph2 = ph * 0.5f;
            const float p_minx = px - pw2, p_maxx = px + pw2;
            const float p_miny = py - ph2, p_maxy = py + ph2;

            float tw2 = tw * 0.5f, th2 = th * 0.5f;
            float iw = fmaxf(fminf(p_maxx, tx + tw2) - fmaxf(p_minx, tx - tw2), 0.f);
            float ih = fmaxf(fminf(p_maxy, ty + th2) - fmaxf(p_miny, ty - th2), 0.f);
            float inter = iw * ih;
            float iou = inter / (pw * ph + tw * th - inter);
            const float true_conf = iou * yt4;

            // ---- classes: lane g owns indices [5g, 5g+5) (disjoint, ascending) ----
            float pv[5];
            float amax = -INFINITY; int aidx = 0x7fffffff;
            float lmax = -INFINITY;
            #pragma unroll
            for (int k = 0; k < 5; ++k) {
                const int c = 5 * g + k;
                const float tv  = yt[5 + c];
                const float pvk = yp[5 + c];
                pv[k] = pvk;
                if (tv > amax) { amax = tv; aidx = c; }   // strict > = first-max
                lmax = fmaxf(lmax, pvk);
            }
            // 16-lane reduce (lower lane = lower index -> tiebreak by min idx)
            #pragma unroll
            for (int m = 1; m <= 8; m <<= 1) {
                float ov = __shfl_xor(amax, m);
                int   oi = __shfl_xor(aidx, m);
                if (ov > amax || (ov == amax && oi < aidx)) { amax = ov; aidx = oi; }
                lmax = fmaxf(lmax, __shfl_xor(lmax, m));
            }

            // pass 2 entirely from registers
            float lsum = 0.f;
            #pragma unroll
            for (int k = 0; k < 5; ++k) lsum += expf(pv[k] - lmax);
            #pragma unroll
            for (int m = 1; m <= 8; m <<= 1) lsum += __shfl_xor(lsum, m);

            const float sel = yp[5 + aidx];          // LDS broadcast read
            const float ce  = -(sel - lmax - logf(lsum));

            // ---- best IoU over 50 true boxes (16-way split; L2-hot) ----
            const float4* __restrict__ tb = (const float4*)(tboxes + (size_t)b * T_BOXES * 4);
            float best = -INFINITY;
            #pragma unroll
            for (int k2 = 0; k2 < 4; ++k2) {
                const int t = g + LPC * k2;
                if (t < T_BOXES) {
                    float4 bx = tb[t];
                    float bw2 = bx.z * 0.5f, bh2 = bx.w * 0.5f;
                    float iw2 = fmaxf(fminf(p_maxx, bx.x + bw2) - fmaxf(p_minx, bx.x - bw2), 0.f);
                    float ih2 = fmaxf(fminf(p_maxy, bx.y + bh2) - fmaxf(p_miny, bx.y - bh2), 0.f);
                    float ia = iw2 * ih2;
                    float r  = ia / (pw * ph + bx.z * bx.w - ia);
                    best = fmaxf(best, r);
                }
            }
            #pragma unroll
            for (int m = 1; m <= 8; m <<= 1)
                best = fmaxf(best, __shfl_xor(best, m));

            // ---- per-cell contributions accumulate on lane g==0 across tiles ----
            if (g == 0) {
                const float cm = yt4;  // coord_mask (COORD_FACTOR=1)
                p_xy += (double)(((tx - px) * (tx - px) + (ty - py) * (ty - py)) * cm);
                p_wh += (double)(((tw - pw) * (tw - pw) + (th - ph) * (th - ph)) * cm);
                float conf_mask = ((best < 0.6f) ? 1.f : 0.f) * (1.f - yt4)  // NO_OBJECT_FACTOR=1
                                + true_conf * 5.f;                            // OBJECT_FACTOR=5
                p_conf += (double)((true_conf - pconf) * (true_conf - pconf) * conf_mask);
                p_ce   += (double)(ce * yt4);                                 // CLASS_FACTOR=1
                p_nc   += (cm > 0.f)        ? 1.0 : 0.0;
                p_nf   += (conf_mask > 0.f) ? 1.0 : 0.0;
                p_ncl  += (yt4 > 0.f)       ? 1.0 : 0.0;
            }
        }
    }

    // ---- block reduction: contributors are lanes 0,16,32,48 of each wave ----
    double v[7] = {p_xy, p_wh, p_conf, p_ce, p_nc, p_nf, p_ncl};
    #pragma unroll
    for (int k = 0; k < 7; ++k) {
        v[k] += __shfl_xor(v[k], 16);
        v[k] += __shfl_xor(v[k], 32);
    }
    const int wave = tid >> 6, lane = tid & 63;
    if (lane == 0) {
        #pragma unroll
        for (int k = 0; k < 7; ++k) red[wave][k] = v[k];
    }
    __syncthreads();
    if (tid < 8) {
        double s = 0.0;
        if (tid < 7) {
            #pragma unroll
            for (int wv = 0; wv < 8; ++wv) s += red[wv][tid];
        }
        if (USE_ATOMIC) {
            if (tid < 7) unsafeAtomicAdd(&partials[tid], s);
        } else {
            partials[(size_t)blockIdx.x * 8 + tid] = s;   // [7] stores the 0 pad
        }
    }
}

// Reduce nblocks partial rows -> final scalar loss.
template <int USE_ATOMIC>
__global__ __launch_bounds__(1024)
void yolo_loss_final(const double* __restrict__ partials,
                     float* __restrict__ out, int nblocks)
{
    __shared__ double red[16][8];
    const int tid = threadIdx.x;

    if (USE_ATOMIC) {
        if (tid == 0) {
            double nbc  = partials[4] + 1e-6;
            double nbf  = partials[5] + 1e-6;
            double nbcl = partials[6] + 1e-6;
            out[0] = (float)(partials[0] / nbc * 0.5 + partials[1] / nbc * 0.5 +
                             partials[2] / nbf * 0.5 + partials[3] / nbcl);
        }
        return;
    }

    double v[7] = {0, 0, 0, 0, 0, 0, 0};
    for (int i = tid; i < nblocks; i += 1024) {
        const double4* p = (const double4*)(partials + (size_t)i * 8);  // 32B-aligned
        double4 a = p[0];
        double4 b = p[1];
        v[0] += a.x; v[1] += a.y; v[2] += a.z; v[3] += a.w;
        v[4] += b.x; v[5] += b.y; v[6] += b.z;   // b.w is the zero pad
    }
    #pragma unroll
    for (int k = 0; k < 7; ++k) {
        #pragma unroll
        for (int off = 32; off > 0; off >>= 1)
            v[k] += __shfl_down(v[k], off);
    }
    const int wave = tid >> 6, lane = tid & 63;
    if (lane == 0) {
        #pragma unroll
        for (int k = 0; k < 7; ++k) red[wave][k] = v[k];
    }
    __syncthreads();
    if (tid == 0) {
        double s[7];
        #pragma unroll
        for (int k = 0; k < 7; ++k) {
            double acc = 0.0;
            #pragma unroll
            for (int wv = 0; wv < 16; ++wv) acc += red[wv][k];
            s[k] = acc;
        }
        double nbc  = s[4] + 1e-6;
        double nbf  = s[5] + 1e-6;
        double nbcl = s[6] + 1e-6;
        out[0] = (float)(s[0] / nbc * 0.5 + s[1] / nbc * 0.5 +
                         s[2] / nbf * 0.5 + s[3] / nbcl);
    }
}

extern "C" void kernel_launch(void* const* d_in, const int* in_sizes, int n_in,
                              void* d_out, int out_size, void* d_ws, size_t ws_size,
                              hipStream_t stream)
{
    const float* y_true = (const float*)d_in[0];
    const float* y_pred = (const float*)d_in[1];
    const float* tboxes = (const float*)d_in[2];
    float* out  = (float*)d_out;
    double* ws  = (double*)d_ws;

    const int n_cells = in_sizes[0] / REC;                 // B*13*13*5 = 216320
    const int ntiles  = (n_cells + CPT - 1) / CPT;         // 6760 for B=256
    const int grid    = ntiles < MAX_GRID ? ntiles : MAX_GRID;
    const size_t need = (size_t)grid * 8 * sizeof(double);

    if (ws_size >= need) {
        // contention-free path: per-block partial stores + tree reduce
        yolo_loss_main<0><<<grid, THREADS, 0, stream>>>(y_true, y_pred, tboxes, ws,
                                                        n_cells, ntiles);
        yolo_loss_final<0><<<1, 1024, 0, stream>>>(ws, out, grid);
    } else {
        // fallback: atomic accumulation into ws[0..6]
        hipMemsetAsync(d_ws, 0, 7 * sizeof(double), stream);
        yolo_loss_main<1><<<grid, THREADS, 0, stream>>>(y_true, y_pred, tboxes, ws,
                                                        n_cells, ntiles);
        yolo_loss_final<1><<<1, 64, 0, stream>>>(ws, out, grid);
    }
}

// Round 6
// 178.457 us; speedup vs baseline: 1.1479x; 1.1479x over previous
//
#include <hip/hip_runtime.h>
#include <math.h>

// Problem constants (from reference)
#define GRID_HW   13
#define NBOX      5
#define NCLASS    80
#define REC       85                       // 5 + NCLASS floats per cell
#define CPB_CELLS (GRID_HW*GRID_HW*NBOX)   // 845 cells per batch element
#define T_BOXES   50
#define THREADS   512
#define CPT       64                       // cells per block/tile
#define LPC       8                        // lanes per cell
#define TILE_FLOATS (CPT*REC)              // 5440 floats per array per tile
#define TILE_F4     (TILE_FLOATS/4)        // 1360 float4 per array per tile

__device__ __constant__ float c_anchors[10] = {
    0.57273f, 0.677385f, 1.87446f, 2.06253f, 3.33843f,
    5.47434f, 7.88282f, 3.52778f, 9.77052f, 9.16828f};

// partial row per block (64 B): [0]=sum_xy [1]=sum_wh [2]=sum_conf [3]=sum_ce
// [4]=nb_coord [5]=nb_conf [6]=nb_class [7]=0 pad (for double4 in reducer)
template <int USE_ATOMIC>
__global__ __launch_bounds__(THREADS, 6)       // VGPR cap 85 -> 3 blocks/CU (LDS-limited), no spill
void yolo_loss_main(const float* __restrict__ y_true,
                    const float* __restrict__ y_pred,
                    const float* __restrict__ tboxes,
                    double* __restrict__ partials,
                    int n_cells)
{
    __shared__ float4 lbuf4[2 * TILE_F4];     // 43520 B staged tile (yt | yp)
    __shared__ double red[8][8];              // 8 waves

    float* const lt = (float*)lbuf4;          // y_true tile
    float* const lp = lt + TILE_FLOATS;       // y_pred tile

    const int tid = threadIdx.x;
    const int o   = tid & (LPC - 1);          // lane within cell group (0..7)
    const int cl  = tid >> 3;                 // cell within tile (0..63)
    const int cellbase = blockIdx.x * CPT;

    // ---- stage tile: perfectly coalesced float4 global -> LDS ----
    {
        const int remc = min(CPT, n_cells - cellbase);
        if (remc == CPT) {
            const float4* __restrict__ gt4 = (const float4*)(y_true + (size_t)cellbase * REC);
            const float4* __restrict__ gp4 = (const float4*)(y_pred + (size_t)cellbase * REC);
            #pragma unroll
            for (int r = 0; r < 6; ++r) {
                const int idx = r * THREADS + tid;
                if (idx < 2 * TILE_F4)
                    lbuf4[idx] = (idx < TILE_F4) ? gt4[idx] : gp4[idx - TILE_F4];
            }
        } else {
            const int nf = remc * REC;
            const size_t base = (size_t)cellbase * REC;
            for (int i = tid; i < nf; i += THREADS) {
                lt[i] = y_true[base + i];
                lp[i] = y_pred[base + i];
            }
        }
    }
    __syncthreads();

    // per-cell contributions, float (one cell per thread-group; no accumulation)
    float f_xy = 0.f, f_wh = 0.f, f_conf = 0.f, f_ce = 0.f;
    float f_nc = 0.f, f_nf = 0.f, f_ncl = 0.f;

    const int cell = cellbase + cl;
    if (cell < n_cells) {
        // decode (b, h, w, box)
        int b    = cell / CPB_CELLS;
        int rem  = cell - b * CPB_CELLS;
        int h    = rem / (GRID_HW * NBOX);
        int rem2 = rem - h * (GRID_HW * NBOX);
        int w    = rem2 / NBOX;
        int box  = rem2 - w * NBOX;

        const float* __restrict__ yt = lt + cl * REC;
        const float* __restrict__ yp = lp + cl * REC;

        // head (LDS broadcast reads within the 8-lane group)
        const float tx = yt[0], ty = yt[1], tw = yt[2], th = yt[3], yt4 = yt[4];
        const float r0 = yp[0], r1 = yp[1], r2 = yp[2], r3 = yp[3], r4 = yp[4];

        const float px = 1.f / (1.f + expf(-r0)) + (float)w;
        const float py = 1.f / (1.f + expf(-r1)) + (float)h;
        const float pw = expf(r2) * c_anchors[2 * box];
        const float ph = expf(r3) * c_anchors[2 * box + 1];
        const float pconf = 1.f / (1.f + expf(-r4));

        const float pw2 = pw * 0.5f, ph2 = ph * 0.5f;
        const float p_minx = px - pw2, p_maxx = px + pw2;
        const float p_miny = py - ph2, p_maxy = py + ph2;

        float tw2 = tw * 0.5f, th2 = th * 0.5f;
        float iw = fmaxf(fminf(p_maxx, tx + tw2) - fmaxf(p_minx, tx - tw2), 0.f);
        float ih = fmaxf(fminf(p_maxy, ty + th2) - fmaxf(p_miny, ty - th2), 0.f);
        float inter = iw * ih;
        float iou = inter / (pw * ph + tw * th - inter);
        const float true_conf = iou * yt4;

        // ---- pass 1: y_true argmax + y_pred max (lane o owns classes o+8k) ----
        float amax = -INFINITY; int aidx = 0x7fffffff;
        float lmax = -INFINITY;
        #pragma unroll
        for (int k = 0; k < NCLASS / LPC; ++k) {
            const int c = o + LPC * k;
            const float tv = yt[5 + c];
            const float pv = yp[5 + c];
            if (tv > amax) { amax = tv; aidx = c; }   // strict > : first-max within lane
            lmax = fmaxf(lmax, pv);
        }
        // 8-lane reduce; explicit min-index tiebreak across lanes
        #pragma unroll
        for (int m = 1; m <= 4; m <<= 1) {
            float ov = __shfl_xor(amax, m);
            int   oi = __shfl_xor(aidx, m);
            if (ov > amax || (ov == amax && oi < aidx)) { amax = ov; aidx = oi; }
            lmax = fmaxf(lmax, __shfl_xor(lmax, m));
        }

        // ---- pass 2: sum exp (LDS re-reads, conflict-light) ----
        float lsum = 0.f;
        #pragma unroll
        for (int k = 0; k < NCLASS / LPC; ++k)
            lsum += expf(yp[5 + o + LPC * k] - lmax);
        #pragma unroll
        for (int m = 1; m <= 4; m <<= 1)
            lsum += __shfl_xor(lsum, m);

        const float sel = yp[5 + aidx];              // LDS broadcast read
        const float ce  = -(sel - lmax - logf(lsum));

        // ---- best IoU over 50 true boxes (8-way split; L2-hot) ----
        const float4* __restrict__ tb = (const float4*)(tboxes + (size_t)b * T_BOXES * 4);
        float best = -INFINITY;
        #pragma unroll
        for (int k2 = 0; k2 < 7; ++k2) {
            const int t = o + LPC * k2;
            if (t < T_BOXES) {
                float4 bx = tb[t];
                float bw2 = bx.z * 0.5f, bh2 = bx.w * 0.5f;
                float iw2 = fmaxf(fminf(p_maxx, bx.x + bw2) - fmaxf(p_minx, bx.x - bw2), 0.f);
                float ih2 = fmaxf(fminf(p_maxy, bx.y + bh2) - fmaxf(p_miny, bx.y - bh2), 0.f);
                float ia = iw2 * ih2;
                float r  = ia / (pw * ph + bx.z * bx.w - ia);
                best = fmaxf(best, r);
            }
        }
        #pragma unroll
        for (int m = 1; m <= 4; m <<= 1)
            best = fmaxf(best, __shfl_xor(best, m));

        // ---- per-cell contributions (lane o==0 only) ----
        if (o == 0) {
            const float cm = yt4;  // coord_mask (COORD_FACTOR=1)
            f_xy = ((tx - px) * (tx - px) + (ty - py) * (ty - py)) * cm;
            f_wh = ((tw - pw) * (tw - pw) + (th - ph) * (th - ph)) * cm;
            float conf_mask = ((best < 0.6f) ? 1.f : 0.f) * (1.f - yt4)  // NO_OBJECT_FACTOR=1
                            + true_conf * 5.f;                            // OBJECT_FACTOR=5
            f_conf = (true_conf - pconf) * (true_conf - pconf) * conf_mask;
            f_ce   = ce * yt4;                                            // CLASS_FACTOR=1
            f_nc   = (cm > 0.f)        ? 1.f : 0.f;
            f_nf   = (conf_mask > 0.f) ? 1.f : 0.f;
            f_ncl  = (yt4 > 0.f)       ? 1.f : 0.f;
        }
    }

    // ---- block reduction: contributors are lanes 0,8,...,56 of each wave ----
    double v[7] = {(double)f_xy, (double)f_wh, (double)f_conf, (double)f_ce,
                   (double)f_nc, (double)f_nf, (double)f_ncl};
    #pragma unroll
    for (int k = 0; k < 7; ++k) {
        v[k] += __shfl_xor(v[k], 8);
        v[k] += __shfl_xor(v[k], 16);
        v[k] += __shfl_xor(v[k], 32);
    }
    const int wave = tid >> 6, lane = tid & 63;
    if (lane == 0) {
        #pragma unroll
        for (int k = 0; k < 7; ++k) red[wave][k] = v[k];
    }
    __syncthreads();
    if (tid < 8) {
        double s = 0.0;
        if (tid < 7) {
            #pragma unroll
            for (int wv = 0; wv < 8; ++wv) s += red[wv][tid];
        }
        if (USE_ATOMIC) {
            if (tid < 7) unsafeAtomicAdd(&partials[tid], s);
        } else {
            partials[(size_t)blockIdx.x * 8 + tid] = s;   // [7] stores the 0 pad
        }
    }
}

// Reduce nblocks partial rows -> final scalar loss.
template <int USE_ATOMIC>
__global__ __launch_bounds__(1024)
void yolo_loss_final(const double* __restrict__ partials,
                     float* __restrict__ out, int nblocks)
{
    __shared__ double red[16][8];
    const int tid = threadIdx.x;

    if (USE_ATOMIC) {
        if (tid == 0) {
            double nbc  = partials[4] + 1e-6;
            double nbf  = partials[5] + 1e-6;
            double nbcl = partials[6] + 1e-6;
            out[0] = (float)(partials[0] / nbc * 0.5 + partials[1] / nbc * 0.5 +
                             partials[2] / nbf * 0.5 + partials[3] / nbcl);
        }
        return;
    }

    double v[7] = {0, 0, 0, 0, 0, 0, 0};
    for (int i = tid; i < nblocks; i += 1024) {
        const double4* p = (const double4*)(partials + (size_t)i * 8);  // 32B-aligned
        double4 a = p[0];
        double4 b = p[1];
        v[0] += a.x; v[1] += a.y; v[2] += a.z; v[3] += a.w;
        v[4] += b.x; v[5] += b.y; v[6] += b.z;   // b.w is the zero pad
    }
    #pragma unroll
    for (int k = 0; k < 7; ++k) {
        #pragma unroll
        for (int off = 32; off > 0; off >>= 1)
            v[k] += __shfl_down(v[k], off);
    }
    const int wave = tid >> 6, lane = tid & 63;
    if (lane == 0) {
        #pragma unroll
        for (int k = 0; k < 7; ++k) red[wave][k] = v[k];
    }
    __syncthreads();
    if (tid == 0) {
        double s[7];
        #pragma unroll
        for (int k = 0; k < 7; ++k) {
            double acc = 0.0;
            #pragma unroll
            for (int wv = 0; wv < 16; ++wv) acc += red[wv][k];
            s[k] = acc;
        }
        double nbc  = s[4] + 1e-6;
        double nbf  = s[5] + 1e-6;
        double nbcl = s[6] + 1e-6;
        out[0] = (float)(s[0] / nbc * 0.5 + s[1] / nbc * 0.5 +
                         s[2] / nbf * 0.5 + s[3] / nbcl);
    }
}

extern "C" void kernel_launch(void* const* d_in, const int* in_sizes, int n_in,
                              void* d_out, int out_size, void* d_ws, size_t ws_size,
                              hipStream_t stream)
{
    const float* y_true = (const float*)d_in[0];
    const float* y_pred = (const float*)d_in[1];
    const float* tboxes = (const float*)d_in[2];
    float* out  = (float*)d_out;
    double* ws  = (double*)d_ws;

    const int n_cells = in_sizes[0] / REC;                 // B*13*13*5 = 216320
    const int blocks  = (n_cells + CPT - 1) / CPT;         // 3380 for B=256
    const size_t need = (size_t)blocks * 8 * sizeof(double);

    if (ws_size >= need) {
        // contention-free path: per-block partial stores + tree reduce
        yolo_loss_main<0><<<blocks, THREADS, 0, stream>>>(y_true, y_pred, tboxes, ws, n_cells);
        yolo_loss_final<0><<<1, 1024, 0, stream>>>(ws, out, blocks);
    } else {
        // fallback: atomic accumulation into ws[0..6]
        hipMemsetAsync(d_ws, 0, 7 * sizeof(double), stream);
        yolo_loss_main<1><<<blocks, THREADS, 0, stream>>>(y_true, y_pred, tboxes, ws, n_cells);
        yolo_loss_final<1><<<1, 64, 0, stream>>>(ws, out, blocks);
    }
}